// Round 1
// baseline (750.470 us; speedup 1.0000x reference)
//
#include <hip/hip_runtime.h>
#include <stdint.h>

// Problem constants
#define NN    50000
#define EE    800000
#define IN_C  128
#define ED_C  64
#define HID_C 256
#define BB    128
#define KK    1000
#define G1_C  128
#define NV    50176   // NN padded to 196*256 for scan

// Dtype model (R1/R2 forensics): fp32 inputs, int32 indices, fp32 outputs.
// R4 counters: k_edge atomic-bound (252G dword-atomics/s). R5: sort-by-dst +
// quad run-merge (~32 atomics/col/block). R6 (this): block-wide segmented
// reduction via LDS transpose -> 2 atomics/col/block (block-interior dst runs
// are exclusive to one block => plain stores into zero-initialized agg).

typedef __attribute__((ext_vector_type(8))) short bfrag;   // 8 x bf16
typedef __attribute__((ext_vector_type(4))) float f4acc;   // 4 x f32 acc

__device__ __forceinline__ unsigned short f2bs(float f){   // f32 -> bf16 (RNE)
  unsigned u = __float_as_uint(f);
  return (unsigned short)((u + 0x7fffu + ((u >> 16) & 1u)) >> 16);
}
__device__ __forceinline__ float bs2f(unsigned short s){
  return __uint_as_float(((unsigned)s) << 16);
}

__device__ __forceinline__ void atomicMaxFloat(float* addr, float val){
  int old = __float_as_int(*addr);
  while (__int_as_float(old) < val){
    int assumed = old;
    old = atomicCAS((int*)addr, assumed, __float_as_int(val));
    if (old == assumed) break;
  }
}

// ---------------- prep: cast+transpose weights to bf16 (Wt[n][k] = W[k][n]) --
__global__ __launch_bounds__(256) void k_prep(
    const float* __restrict__ We, const float* __restrict__ W1,
    const float* __restrict__ W2, const float* __restrict__ Wg1,
    unsigned short* __restrict__ Wet, unsigned short* __restrict__ W1t,
    unsigned short* __restrict__ W2t, unsigned short* __restrict__ Wg1t)
{
  int i = blockIdx.x * 256 + threadIdx.x;
  if (i < 128 * 64){ int c = i >> 6, k = i & 63;  Wet[i]  = f2bs(We[k * 128 + c]); }
  if (i < 256 * 128){ int n = i >> 7, k = i & 127; W1t[i]  = f2bs(W1[k * 256 + n]); }
  if (i < 256 * 256){ int n = i >> 8, k = i & 255; W2t[i]  = f2bs(W2[k * 256 + n]); }
  if (i < 128 * 256){ int n = i >> 8, k = i & 255; Wg1t[i] = f2bs(Wg1[k * 128 + n]); }
}

// ---------------- init: zero agg/cnt/fill/aux/denom/pooled, gmax=-1e30 ----
__global__ __launch_bounds__(256) void k_init(float* __restrict__ agg,
                                              int* __restrict__ cnt,
                                              int* __restrict__ fill,
                                              int* __restrict__ aux,
                                              float* __restrict__ gmax,
                                              float* __restrict__ denom,
                                              float* __restrict__ pooled){
  size_t i = (size_t)blockIdx.x * 256 + threadIdx.x;
  if (i < (size_t)NN * IN_C) agg[i] = 0.f;
  if (i < NV){ cnt[i] = 0; fill[i] = 0; }
  if (i < 256) aux[i] = 0;
  if (i < BB){ gmax[i] = -1e30f; denom[i] = 0.f; }
  if (i < BB * HID_C) pooled[i] = 0.f;
}

// ---------------- counting sort by dst: hist -> scan -> scatter ----------
__global__ __launch_bounds__(256) void k_hist(const int* __restrict__ ei,
                                              int* __restrict__ cnt){
  int e = blockIdx.x * 256 + threadIdx.x;
  if (e < EE) atomicAdd(&cnt[ei[EE + e]], 1);
}

__global__ __launch_bounds__(256) void k_scan1(const int* __restrict__ cnt,
                                               int* __restrict__ off,
                                               int* __restrict__ aux){
  __shared__ int s[256];
  int t = threadIdx.x, i = blockIdx.x * 256 + t;
  int val = cnt[i];
  s[t] = val; __syncthreads();
#pragma unroll
  for (int o = 1; o < 256; o <<= 1){
    int v = (t >= o) ? s[t - o] : 0;
    __syncthreads();
    s[t] += v;
    __syncthreads();
  }
  off[i] = s[t] - val;
  if (t == 255) aux[blockIdx.x] = s[255];
}

__global__ __launch_bounds__(256) void k_scan2(int* __restrict__ aux){
  __shared__ int s[256];
  int t = threadIdx.x;
  int val = aux[t];
  s[t] = val; __syncthreads();
#pragma unroll
  for (int o = 1; o < 256; o <<= 1){
    int v = (t >= o) ? s[t - o] : 0;
    __syncthreads();
    s[t] += v;
    __syncthreads();
  }
  aux[t] = s[t] - val;
}

__global__ __launch_bounds__(256) void k_scan3(int* __restrict__ off,
                                               const int* __restrict__ aux){
  int i = blockIdx.x * 256 + threadIdx.x;
  off[i] += aux[blockIdx.x];
}

__global__ __launch_bounds__(256) void k_scatter(const int* __restrict__ ei,
                                                 const int* __restrict__ off,
                                                 int* __restrict__ fill,
                                                 uint4* __restrict__ sorted){
  int e = blockIdx.x * 256 + threadIdx.x;
  if (e < EE){
    int s = ei[e], d = ei[EE + e];
    int pos = off[d] + atomicAdd(&fill[d], 1);
    sorted[pos] = make_uint4((unsigned)e, (unsigned)s, (unsigned)d, 0u);
  }
}

// ---------------- edge stage (MFMA, dst-sorted, block segmented-reduce) ---
// Block = 256 thr / 4 waves; tile = 128 sorted slots x 128 channels.
// Epilogue: msg tile -> LDS (f32, stride 130: 2 lanes/bank = free), then
// 128 cols x 2 half-chunks of 64 rows walk serially. dst runs interior to
// the block are exclusive (sorted) => plain store; only runs touching row 0
// or row 127 need atomicAdd. ~2 atomics/col/block vs 32 with quad-merge.
__global__ __launch_bounds__(256) void k_edge2(
    const float* __restrict__ x, const uint4* __restrict__ sorted,
    const float* __restrict__ edge_attr,
    const unsigned short* __restrict__ Wet, const float* __restrict__ be,
    float* __restrict__ agg)
{
  __shared__ float msgS[128 * 130];          // 66.5KB; aliased by ea staging
  __shared__ uint4 sE[128];
  __shared__ float bridgeS[128];
  unsigned short* eaS = (unsigned short*)msgS;   // 128*72 shorts = 18.4KB

  const int tid = threadIdx.x;
  const int e0 = blockIdx.x * 128;
  if (tid < 128) sE[tid] = sorted[e0 + tid];
  __syncthreads();
#pragma unroll
  for (int t = 0; t < 8; ++t){
    int f4 = t * 256 + tid;
    int er = f4 >> 4;
    int kk = (f4 & 15) * 4;
    int eid = (int)sE[er].x;
    const float4 v = *(const float4*)(edge_attr + (size_t)eid * ED_C + kk);
    unsigned p0 = (unsigned)f2bs(v.x) | ((unsigned)f2bs(v.y) << 16);
    unsigned p1 = (unsigned)f2bs(v.z) | ((unsigned)f2bs(v.w) << 16);
    *(uint2*)&eaS[er * 72 + kk] = make_uint2(p0, p1);
  }
  __syncthreads();

  const int lane = tid & 63, wv = tid >> 6;
  const int q = lane >> 4, l15 = lane & 15;

  f4acc acc[2][8];
  const f4acc zz = {0.f, 0.f, 0.f, 0.f};
#pragma unroll
  for (int mt = 0; mt < 2; ++mt)
#pragma unroll
    for (int nt = 0; nt < 8; ++nt) acc[mt][nt] = zz;

#pragma unroll
  for (int ks = 0; ks < 2; ++ks){
    bfrag a[2], b[8];
#pragma unroll
    for (int mt = 0; mt < 2; ++mt){
      int m = wv * 32 + mt * 16 + l15;
      a[mt] = *(const bfrag*)&eaS[m * 72 + ks * 32 + q * 8];
    }
#pragma unroll
    for (int nt = 0; nt < 8; ++nt){
      int c = nt * 16 + l15;
      b[nt] = *(const bfrag*)(Wet + c * ED_C + ks * 32 + q * 8);
    }
#pragma unroll
    for (int mt = 0; mt < 2; ++mt)
#pragma unroll
      for (int nt = 0; nt < 8; ++nt)
        acc[mt][nt] = __builtin_amdgcn_mfma_f32_16x16x32_bf16(a[mt], b[nt], acc[mt][nt], 0, 0, 0);
  }

  float bev[8];
#pragma unroll
  for (int nt = 0; nt < 8; ++nt) bev[nt] = be[nt * 16 + l15];

  __syncthreads();   // all eaS reads done before msgS overwrites it

  // x-gather + bias + ReLU -> LDS message tile [row 0..127][col 0..127]
#pragma unroll
  for (int mt = 0; mt < 2; ++mt){
    const int g = wv * 32 + mt * 16 + q * 4;
    int sr[4];
#pragma unroll
    for (int r = 0; r < 4; ++r) sr[r] = (int)sE[g + r].y;
#pragma unroll
    for (int nt = 0; nt < 8; ++nt){
      int c = nt * 16 + l15;
#pragma unroll
      for (int r = 0; r < 4; ++r){
        float v = acc[mt][nt][r] + bev[nt] + x[(size_t)sr[r] * IN_C + c];
        v = v > 0.f ? v : 0.f;
        msgS[(g + r) * 130 + c] = v;
      }
    }
  }
  __syncthreads();

  // column-parallel segmented reduction: 128 cols x 2 half-chunks of 64 rows.
  // All branches are wave-uniform (same row sequence across a wave's lanes),
  // so every flush is a coalesced 256B store/atomic burst.
  const int col = tid & 127;
  const int h = tid >> 7;                 // half: rows [h*64, h*64+64)
  const int rbeg = h * 64, rend = rbeg + 64;
  const bool bridged = ((int)sE[63].z == (int)sE[64].z);

  int cur = (int)sE[rbeg].z;
  int runstart = rbeg;
  float run = 0.f;
  float firstSum = 0.f; int firstDst = cur;
  bool firstPending = (h == 1);           // h1 defers its first run

  for (int r = rbeg; r < rend; ++r){
    int d = (int)sE[r].z;
    if (d != cur){
      if (firstPending){
        firstSum = run; firstDst = cur; firstPending = false;
      } else {
        // h0: atomic iff touches row 0; h1 in-loop runs are block-interior
        if (h == 0 && runstart == 0)
          atomicAdd(&agg[(size_t)cur * IN_C + col], run);
        else
          agg[(size_t)cur * IN_C + col] = run;
      }
      run = 0.f; cur = d; runstart = r;
    }
    run += msgS[r * 130 + col];
  }

  if (h == 0){
    if (bridged){
      bridgeS[col] = run;                 // hand tail to h1 (same dst)
      // if h0 was single-run (runstart==0), nothing flushed; h1 resolves it
    } else {
      if (runstart == 0) atomicAdd(&agg[(size_t)cur * IN_C + col], run);
      else               agg[(size_t)cur * IN_C + col] = run;
    }
  }
  __syncthreads();
  if (h == 1){
    if (firstPending){
      // whole h1 chunk is one run; touches row 127 -> atomic
      float s = run + (bridged ? bridgeS[col] : 0.f);
      atomicAdd(&agg[(size_t)cur * IN_C + col], s);
    } else {
      // deferred first run
      float s = firstSum + (bridged ? bridgeS[col] : 0.f);
      bool touches0 = bridged && ((int)sE[0].z == firstDst);
      if (touches0) atomicAdd(&agg[(size_t)firstDst * IN_C + col], s);
      else          agg[(size_t)firstDst * IN_C + col] = s;
      // last run touches row 127 -> atomic (may continue in next block)
      atomicAdd(&agg[(size_t)cur * IN_C + col], run);
    }
  }
}

// ---------------- h0 = agg + x -> bf16 ----------------
__global__ __launch_bounds__(256) void k_h0(const float* __restrict__ agg,
                                            const float* __restrict__ x,
                                            unsigned short* __restrict__ h0b){
  int i = blockIdx.x * 256 + threadIdx.x;
  if (i < NN * IN_C) h0b[i] = f2bs(agg[i] + x[i]);
}

// ---------------- MFMA GEMM with LDS-staged fragments --------------------
// out[m][c] = A[m][:K].Wt[c][:K] + bias[c]; block 64m x 128n, 4 waves 2x2.
// A/B sub-tiles staged per 32-k step; 40-short row stride (80B: 16B-aligned,
// <=2-way LDS bank aliasing = free).
template<int K, bool RELU, bool OF32, bool OB16>
__global__ __launch_bounds__(256) void k_gemm(
    const unsigned short* __restrict__ A, const unsigned short* __restrict__ Wt,
    const float* __restrict__ bias, float* __restrict__ outf,
    unsigned short* __restrict__ outb, int M, int Ntot)
{
  __shared__ unsigned short aS[64 * 40];
  __shared__ unsigned short bS[128 * 40];
  const int tid = threadIdx.x;
  const int lane = tid & 63, wv = tid >> 6;
  const int wi = wv >> 1, wj = wv & 1;
  const int q = lane >> 4, l15 = lane & 15;
  const int mb0 = blockIdx.x * 64;
  const int nb0 = blockIdx.y * 128;
  const int arow = tid >> 2, achk = tid & 3;

  f4acc acc[2][4];
  const f4acc zz = {0.f, 0.f, 0.f, 0.f};
#pragma unroll
  for (int mt = 0; mt < 2; ++mt)
#pragma unroll
    for (int nt = 0; nt < 4; ++nt) acc[mt][nt] = zz;

  for (int ks = 0; ks < K / 32; ++ks){
    {
      int m = mb0 + arow; if (m >= M) m = M - 1;
      const uint4 v = *(const uint4*)(A + (size_t)m * K + ks * 32 + achk * 8);
      *(uint4*)&aS[arow * 40 + achk * 8] = v;
    }
#pragma unroll
    for (int i = 0; i < 2; ++i){
      int idx = i * 256 + tid;
      int row = idx >> 2, chk = idx & 3;
      const uint4 v = *(const uint4*)(Wt + (size_t)(nb0 + row) * K + ks * 32 + chk * 8);
      *(uint4*)&bS[row * 40 + chk * 8] = v;
    }
    __syncthreads();
    bfrag a[2], b[4];
#pragma unroll
    for (int mt = 0; mt < 2; ++mt)
      a[mt] = *(const bfrag*)&aS[(wi * 32 + mt * 16 + l15) * 40 + q * 8];
#pragma unroll
    for (int nt = 0; nt < 4; ++nt)
      b[nt] = *(const bfrag*)&bS[(wj * 64 + nt * 16 + l15) * 40 + q * 8];
#pragma unroll
    for (int mt = 0; mt < 2; ++mt)
#pragma unroll
      for (int nt = 0; nt < 4; ++nt)
        acc[mt][nt] = __builtin_amdgcn_mfma_f32_16x16x32_bf16(a[mt], b[nt], acc[mt][nt], 0, 0, 0);
    __syncthreads();
  }

  const int mb = mb0 + wi * 32;
  const int nb = nb0 + wj * 64;
#pragma unroll
  for (int nt = 0; nt < 4; ++nt){
    int c = nb + nt * 16 + l15;
    float bv = bias[c];
#pragma unroll
    for (int mt = 0; mt < 2; ++mt){
#pragma unroll
      for (int r = 0; r < 4; ++r){
        int m = mb + mt * 16 + q * 4 + r;
        if (m < M){
          float v = acc[mt][nt][r] + bv;
          if (RELU) v = v > 0.f ? v : 0.f;
          if (OF32) outf[(size_t)m * Ntot + c] = v;
          if (OB16) outb[(size_t)m * Ntot + c] = f2bs(v);
        }
      }
    }
  }
}

// ---------------- gate2: gate[r] = g1[r,:128].Wg2 + bg2 (wave/row) -------
__global__ __launch_bounds__(256) void k_gate2(const float* __restrict__ g1,
                                               const float* __restrict__ Wg2,
                                               const float* __restrict__ bg2,
                                               float* __restrict__ gate, int nrows){
  const int lane = threadIdx.x & 63, wv = threadIdx.x >> 6;
  const float2 w2 = *(const float2*)(Wg2 + lane * 2);
  const float bg = bg2[0];
  for (int r = blockIdx.x * 4 + wv; r < nrows; r += gridDim.x * 4){
    const float2 a2 = *(const float2*)(g1 + (size_t)r * G1_C + lane * 2);
    float p = a2.x * w2.x + a2.y * w2.y;
#pragma unroll
    for (int off = 32; off > 0; off >>= 1) p += __shfl_down(p, off);
    if (lane == 0) gate[r] = p + bg;
  }
}

// ---------------- segment max (batch sorted; block pre-reduce) ----------
__global__ __launch_bounds__(256) void k_gmax(const float* __restrict__ gate,
                                              const int* __restrict__ batch,
                                              float* __restrict__ gmax, int nrows){
  __shared__ float red[256];
  const int tid = threadIdx.x;
  const int n0 = blockIdx.x * 256;
  const int n = n0 + tid;
  const int nlast = (n0 + 255 < nrows) ? n0 + 255 : nrows - 1;
  const int bmin = batch[n0], bmax = batch[nlast];
  float val = -3e38f; int b = bmax;
  if (n < nrows){ b = batch[n]; val = gate[n]; }
  for (int bb = bmin; bb <= bmax; ++bb){
    red[tid] = (b == bb) ? val : -3e38f;
    __syncthreads();
    for (int s = 128; s > 0; s >>= 1){
      if (tid < s) red[tid] = fmaxf(red[tid], red[tid + s]);
      __syncthreads();
    }
    if (tid == 0 && red[0] > -1e37f) atomicMaxFloat(&gmax[bb], red[0]);
    __syncthreads();
  }
}

// ---------------- a = exp(gate - gmax[b]); denom[b] += a ----------------
__global__ __launch_bounds__(256) void k_expsum(const float* __restrict__ gate,
                                                const int* __restrict__ batch,
                                                const float* __restrict__ gmax,
                                                float* __restrict__ aexp,
                                                float* __restrict__ denom, int nrows){
  __shared__ float red[256];
  const int tid = threadIdx.x;
  const int n0 = blockIdx.x * 256;
  const int n = n0 + tid;
  const int nlast = (n0 + 255 < nrows) ? n0 + 255 : nrows - 1;
  const int bmin = batch[n0], bmax = batch[nlast];
  float val = 0.f; int b = bmax;
  if (n < nrows){
    b = batch[n];
    val = expf(gate[n] - gmax[b]);
    aexp[n] = val;
  }
  for (int bb = bmin; bb <= bmax; ++bb){
    red[tid] = (b == bb) ? val : 0.f;
    __syncthreads();
    for (int s = 128; s > 0; s >>= 1){
      if (tid < s) red[tid] += red[tid + s];
      __syncthreads();
    }
    if (tid == 0 && red[0] != 0.f) atomicAdd(&denom[bb], red[0]);
    __syncthreads();
  }
}

// ---------------- pooled[b] += (a/denom[b]) * h2[n] ----------------
__global__ __launch_bounds__(256) void k_pool(const unsigned short* __restrict__ h2b,
                                              const float* __restrict__ aexp,
                                              const float* __restrict__ denom,
                                              const int* __restrict__ batch,
                                              float* __restrict__ pooled, int nrows){
  const int c = threadIdx.x;
  const int n0 = blockIdx.x * 256;
  int n1 = n0 + 256; if (n1 > nrows) n1 = nrows;
  float acc = 0.f;
  int curb = batch[n0];
  for (int n = n0; n < n1; ++n){
    int b = batch[n];
    if (b != curb){
      atomicAdd(&pooled[(size_t)curb * HID_C + c], acc);
      acc = 0.f; curb = b;
    }
    float wgt = aexp[n] / denom[b];
    acc = fmaf(wgt, bs2f(h2b[(size_t)n * HID_C + c]), acc);
  }
  atomicAdd(&pooled[(size_t)curb * HID_C + c], acc);
}

// ---------------- head: logits = pooled @ Wh + bh ----------------
__global__ __launch_bounds__(256) void k_head(const float* __restrict__ pooled,
                                              const float* __restrict__ Wh,
                                              const float* __restrict__ bh,
                                              float* __restrict__ out_logits,
                                              float* __restrict__ out_pooled){
  __shared__ float p[HID_C];
  const int b = blockIdx.x, t = threadIdx.x;
  float pv = pooled[(size_t)b * HID_C + t];
  p[t] = pv;
  out_pooled[(size_t)b * HID_C + t] = pv;
  __syncthreads();
  for (int c = t; c < KK; c += 256){
    float acc = bh[c];
#pragma unroll 8
    for (int k = 0; k < HID_C; ++k)
      acc = fmaf(p[k], Wh[k * KK + c], acc);
    out_logits[(size_t)b * KK + c] = acc;
  }
}

extern "C" void kernel_launch(void* const* d_in, const int* in_sizes, int n_in,
                              void* d_out, int out_size, void* d_ws, size_t ws_size,
                              hipStream_t stream) {
  const float* x   = (const float*)d_in[0];
  const int*   ei  = (const int*)d_in[1];
  const float* ea  = (const float*)d_in[2];
  const int*   batch = (const int*)d_in[3];
  const float* We  = (const float*)d_in[4];
  const float* be  = (const float*)d_in[5];
  const float* W1  = (const float*)d_in[6];
  const float* b1  = (const float*)d_in[7];
  const float* W2  = (const float*)d_in[8];
  const float* b2  = (const float*)d_in[9];
  const float* Wg1 = (const float*)d_in[10];
  const float* bg1 = (const float*)d_in[11];
  const float* Wg2 = (const float*)d_in[12];
  const float* bg2 = (const float*)d_in[13];
  const float* Wh  = (const float*)d_in[14];
  const float* bh  = (const float*)d_in[15];

  float* out_logits = (float*)d_out;
  float* out_pooled = out_logits + (size_t)BB * KK;

  // ws layout: f32 region | h0b | h1b (aliased by sort scratch) | h2b | weights
  float* agg    = (float*)d_ws;                    // N*128 (g1f alias later)
  float* gate   = agg   + (size_t)NN * IN_C;       // N
  float* aexp   = gate  + NN;                      // N
  float* gmax   = aexp  + NN;                      // B
  float* denom  = gmax  + BB;                      // B
  float* pooled = denom + BB;                      // B*256
  float* fend   = pooled + (size_t)BB * HID_C;     // 16B-aligned
  unsigned short* h0b  = (unsigned short*)fend;    // N*128 bf16
  unsigned short* h1b  = h0b + (size_t)NN * IN_C;  // N*256 bf16 (25.6MB)
  unsigned short* h2b  = h1b + (size_t)NN * HID_C; // N*256 bf16
  unsigned short* Wet  = h2b + (size_t)NN * HID_C; // 128*64
  unsigned short* W1t  = Wet + 128 * 64;
  unsigned short* W2t  = W1t + 256 * 128;
  unsigned short* Wg1t = W2t + 256 * 256;
  float* g1f = agg;                                // alias: agg dead after k_h0
  // sort scratch aliases h1b region (dead until gemm1): 12.8MB + 0.6MB < 25.6MB
  uint4* sorted = (uint4*)h1b;                     // EE * 16B
  int* cnt  = (int*)(sorted + EE);                 // NV
  int* off  = cnt + NV;                            // NV
  int* fill = off + NV;                            // NV
  int* aux  = fill + NV;                           // 256

  k_prep<<<256, 256, 0, stream>>>(We, W1, W2, Wg1, Wet, W1t, W2t, Wg1t);
  k_init<<<(NN * IN_C + 255) / 256, 256, 0, stream>>>(agg, cnt, fill, aux, gmax, denom, pooled);
  // counting sort by dst
  k_hist   <<<(EE + 255) / 256, 256, 0, stream>>>(ei, cnt);
  k_scan1  <<<NV / 256, 256, 0, stream>>>(cnt, off, aux);
  k_scan2  <<<1, 256, 0, stream>>>(aux);
  k_scan3  <<<NV / 256, 256, 0, stream>>>(off, aux);
  k_scatter<<<(EE + 255) / 256, 256, 0, stream>>>(ei, off, fill, sorted);
  // edge projection + message + block segmented-reduce scatter
  k_edge2<<<EE / 128, 256, 0, stream>>>(x, sorted, ea, Wet, be, agg);
  k_h0<<<(NN * IN_C + 255) / 256, 256, 0, stream>>>(agg, x, h0b);
  // MLP + gate GEMMs (sort scratch dead from here; h1b reused)
  k_gemm<128, true,  false, true ><<<dim3(782, 2), 256, 0, stream>>>(h0b, W1t, b1, (float*)0, h1b, NN, HID_C);
  k_gemm<256, false, false, true ><<<dim3(782, 2), 256, 0, stream>>>(h1b, W2t, b2, (float*)0, h2b, NN, HID_C);
  k_gemm<256, true,  true,  false><<<dim3(782, 1), 256, 0, stream>>>(h2b, Wg1t, bg1, g1f, (unsigned short*)0, NN, G1_C);
  k_gate2<<<3125, 256, 0, stream>>>(g1f, Wg2, bg2, gate, NN);
  k_gmax  <<<(NN + 255) / 256, 256, 0, stream>>>(gate, batch, gmax, NN);
  k_expsum<<<(NN + 255) / 256, 256, 0, stream>>>(gate, batch, gmax, aexp, denom, NN);
  k_pool  <<<(NN + 255) / 256, 256, 0, stream>>>(h2b, aexp, denom, batch, pooled, NN);
  k_head<<<BB, 256, 0, stream>>>(pooled, Wh, bh, out_logits, out_pooled);
}

// Round 3
// 749.896 us; speedup vs baseline: 1.0008x; 1.0008x over previous
//
#include <hip/hip_runtime.h>
#include <stdint.h>

// Problem constants
#define NN    50000
#define EE    800000
#define IN_C  128
#define ED_C  64
#define HID_C 256
#define BB    128
#define KK    1000
#define G1_C  128
#define NV    50176   // NN padded to 196*256 for scan

// R4: k_edge atomic-bound. R5: sort-by-dst + quad merge. R6: LDS transpose +
// block segmented-reduce (2 atomics/col/block) -> 189us, latency-bound
// (all pipes idle: MfmaUtil 2.7%, VALU 17.8%, HBM 21%). R7 (this; resubmit,
// R2 bench was an infra timeout):
//  - ballot-built run list; reduce walks runs (no per-row dst loads/branches)
//  - x gathered as 16 coalesced float4/thread, issued before MFMA, held in
//    registers (T14 async-stage), folded in via float4 LDS RMW.

typedef __attribute__((ext_vector_type(8))) short bfrag;   // 8 x bf16
typedef __attribute__((ext_vector_type(4))) float f4acc;   // 4 x f32 acc

__device__ __forceinline__ unsigned short f2bs(float f){   // f32 -> bf16 (RNE)
  unsigned u = __float_as_uint(f);
  return (unsigned short)((u + 0x7fffu + ((u >> 16) & 1u)) >> 16);
}
__device__ __forceinline__ float bs2f(unsigned short s){
  return __uint_as_float(((unsigned)s) << 16);
}

__device__ __forceinline__ void atomicMaxFloat(float* addr, float val){
  int old = __float_as_int(*addr);
  while (__int_as_float(old) < val){
    int assumed = old;
    old = atomicCAS((int*)addr, assumed, __float_as_int(val));
    if (old == assumed) break;
  }
}

// ---------------- prep: cast+transpose weights to bf16 (Wt[n][k] = W[k][n]) --
__global__ __launch_bounds__(256) void k_prep(
    const float* __restrict__ We, const float* __restrict__ W1,
    const float* __restrict__ W2, const float* __restrict__ Wg1,
    unsigned short* __restrict__ Wet, unsigned short* __restrict__ W1t,
    unsigned short* __restrict__ W2t, unsigned short* __restrict__ Wg1t)
{
  int i = blockIdx.x * 256 + threadIdx.x;
  if (i < 128 * 64){ int c = i >> 6, k = i & 63;  Wet[i]  = f2bs(We[k * 128 + c]); }
  if (i < 256 * 128){ int n = i >> 7, k = i & 127; W1t[i]  = f2bs(W1[k * 256 + n]); }
  if (i < 256 * 256){ int n = i >> 8, k = i & 255; W2t[i]  = f2bs(W2[k * 256 + n]); }
  if (i < 128 * 256){ int n = i >> 8, k = i & 255; Wg1t[i] = f2bs(Wg1[k * 128 + n]); }
}

// ---------------- init: zero agg/cnt/fill/aux/denom/pooled, gmax=-1e30 ----
__global__ __launch_bounds__(256) void k_init(float* __restrict__ agg,
                                              int* __restrict__ cnt,
                                              int* __restrict__ fill,
                                              int* __restrict__ aux,
                                              float* __restrict__ gmax,
                                              float* __restrict__ denom,
                                              float* __restrict__ pooled){
  size_t i = (size_t)blockIdx.x * 256 + threadIdx.x;
  if (i < (size_t)NN * IN_C) agg[i] = 0.f;
  if (i < NV){ cnt[i] = 0; fill[i] = 0; }
  if (i < 256) aux[i] = 0;
  if (i < BB){ gmax[i] = -1e30f; denom[i] = 0.f; }
  if (i < BB * HID_C) pooled[i] = 0.f;
}

// ---------------- counting sort by dst: hist -> scan -> scatter ----------
__global__ __launch_bounds__(256) void k_hist(const int* __restrict__ ei,
                                              int* __restrict__ cnt){
  int e = blockIdx.x * 256 + threadIdx.x;
  if (e < EE) atomicAdd(&cnt[ei[EE + e]], 1);
}

__global__ __launch_bounds__(256) void k_scan1(const int* __restrict__ cnt,
                                               int* __restrict__ off,
                                               int* __restrict__ aux){
  __shared__ int s[256];
  int t = threadIdx.x, i = blockIdx.x * 256 + t;
  int val = cnt[i];
  s[t] = val; __syncthreads();
#pragma unroll
  for (int o = 1; o < 256; o <<= 1){
    int v = (t >= o) ? s[t - o] : 0;
    __syncthreads();
    s[t] += v;
    __syncthreads();
  }
  off[i] = s[t] - val;
  if (t == 255) aux[blockIdx.x] = s[255];
}

__global__ __launch_bounds__(256) void k_scan2(int* __restrict__ aux){
  __shared__ int s[256];
  int t = threadIdx.x;
  int val = aux[t];
  s[t] = val; __syncthreads();
#pragma unroll
  for (int o = 1; o < 256; o <<= 1){
    int v = (t >= o) ? s[t - o] : 0;
    __syncthreads();
    s[t] += v;
    __syncthreads();
  }
  aux[t] = s[t] - val;
}

__global__ __launch_bounds__(256) void k_scan3(int* __restrict__ off,
                                               const int* __restrict__ aux){
  int i = blockIdx.x * 256 + threadIdx.x;
  off[i] += aux[blockIdx.x];
}

__global__ __launch_bounds__(256) void k_scatter(const int* __restrict__ ei,
                                                 const int* __restrict__ off,
                                                 int* __restrict__ fill,
                                                 uint4* __restrict__ sorted){
  int e = blockIdx.x * 256 + threadIdx.x;
  if (e < EE){
    int s = ei[e], d = ei[EE + e];
    int pos = off[d] + atomicAdd(&fill[d], 1);
    sorted[pos] = make_uint4((unsigned)e, (unsigned)s, (unsigned)d, 0u);
  }
}

// ---------------- edge stage (MFMA, dst-sorted, run-list reduce) ---------
// Block = 256 thr / 4 waves; tile = 128 sorted slots x 128 channels.
// Phases: sE load | x reg-prefetch + ea staging + run-list ballot | MFMA |
// msgS = acc+be | msgS += x (f32 regs), ReLU | per-col run-walk:
// block-interior runs -> plain store, boundary runs -> atomicAdd.
__global__ __launch_bounds__(256, 2) void k_edge2(
    const float* __restrict__ x, const uint4* __restrict__ sorted,
    const float* __restrict__ edge_attr,
    const unsigned short* __restrict__ Wet, const float* __restrict__ be,
    float* __restrict__ agg)
{
  __shared__ float msgS[128 * 132];          // 67.6KB; aliased by ea staging
  __shared__ uint4 sE[128];
  __shared__ unsigned long long maskS[2];
  __shared__ int runStart[132];              // nR starts + sentinel 128
  __shared__ int nRunsS;
  unsigned short* eaS = (unsigned short*)msgS;   // 128*72 shorts = 18.4KB

  const int tid = threadIdx.x;
  const int e0 = blockIdx.x * 128;
  if (tid < 128) sE[tid] = sorted[e0 + tid];
  __syncthreads();                           // S1: sE ready

  // ---- x register prefetch: thread owns (row = tid>>1, 64-col half) ----
  const int xrow = tid >> 1;
  const int xc0 = (tid & 1) * 64;
  const float* xptr = x + (size_t)((int)sE[xrow].y) * IN_C + xc0;
  float4 xr[16];
#pragma unroll
  for (int j = 0; j < 16; ++j) xr[j] = *(const float4*)(xptr + j * 4);

  // ---- run-boundary ballot (waves 0,1 cover the 128 sorted slots) ----
  if (tid < 128){
    bool flag = (tid == 0) || ((int)sE[tid].z != (int)sE[tid - 1].z);
    unsigned long long m = __ballot(flag);
    if ((tid & 63) == 0) maskS[tid >> 6] = m;
  }

  // ---- edge_attr -> bf16 staging ----
#pragma unroll
  for (int t = 0; t < 8; ++t){
    int f4 = t * 256 + tid;
    int er = f4 >> 4;
    int kk = (f4 & 15) * 4;
    int eid = (int)sE[er].x;
    const float4 v = *(const float4*)(edge_attr + (size_t)eid * ED_C + kk);
    unsigned p0 = (unsigned)f2bs(v.x) | ((unsigned)f2bs(v.y) << 16);
    unsigned p1 = (unsigned)f2bs(v.z) | ((unsigned)f2bs(v.w) << 16);
    *(uint2*)&eaS[er * 72 + kk] = make_uint2(p0, p1);
  }
  __syncthreads();                           // S2: eaS + maskS ready

  // ---- finish run list (prefix over ballot masks) ----
  if (tid < 128){
    int lane = tid & 63, wvi = tid >> 6;
    unsigned long long mw = maskS[wvi];
    int pre = __popcll(mw & ((1ull << lane) - 1ull)) + (wvi ? __popcll(maskS[0]) : 0);
    if ((mw >> lane) & 1ull) runStart[pre] = tid;
    if (tid == 0){
      int nr = __popcll(maskS[0]) + __popcll(maskS[1]);
      nRunsS = nr;
      runStart[nr] = 128;
    }
  }

  const int lane = tid & 63, wv = tid >> 6;
  const int q = lane >> 4, l15 = lane & 15;

  f4acc acc[2][8];
  const f4acc zz = {0.f, 0.f, 0.f, 0.f};
#pragma unroll
  for (int mt = 0; mt < 2; ++mt)
#pragma unroll
    for (int nt = 0; nt < 8; ++nt) acc[mt][nt] = zz;

#pragma unroll
  for (int ks = 0; ks < 2; ++ks){
    bfrag a[2], b[8];
#pragma unroll
    for (int mt = 0; mt < 2; ++mt){
      int m = wv * 32 + mt * 16 + l15;
      a[mt] = *(const bfrag*)&eaS[m * 72 + ks * 32 + q * 8];
    }
#pragma unroll
    for (int nt = 0; nt < 8; ++nt){
      int c = nt * 16 + l15;
      b[nt] = *(const bfrag*)(Wet + c * ED_C + ks * 32 + q * 8);
    }
#pragma unroll
    for (int mt = 0; mt < 2; ++mt)
#pragma unroll
      for (int nt = 0; nt < 8; ++nt)
        acc[mt][nt] = __builtin_amdgcn_mfma_f32_16x16x32_bf16(a[mt], b[nt], acc[mt][nt], 0, 0, 0);
  }

  float bev[8];
#pragma unroll
  for (int nt = 0; nt < 8; ++nt) bev[nt] = be[nt * 16 + l15];

  __syncthreads();                           // S3: eaS dead, msgS writable

  // ---- msgS = acc + be (MFMA fragment layout) ----
#pragma unroll
  for (int mt = 0; mt < 2; ++mt){
    const int g = wv * 32 + mt * 16 + q * 4;
#pragma unroll
    for (int nt = 0; nt < 8; ++nt){
      int c = nt * 16 + l15;
#pragma unroll
      for (int r = 0; r < 4; ++r)
        msgS[(g + r) * 132 + c] = acc[mt][nt][r] + bev[nt];
    }
  }
  __syncthreads();                           // S4: msgS (acc+be) complete

  // ---- fold x in from registers, ReLU (float4 LDS RMW) ----
  {
    float* mr = &msgS[xrow * 132 + xc0];
#pragma unroll
    for (int j = 0; j < 16; ++j){
      float4 w = *(float4*)(mr + j * 4);
      const float4 v = xr[j];
      w.x = fmaxf(w.x + v.x, 0.f);
      w.y = fmaxf(w.y + v.y, 0.f);
      w.z = fmaxf(w.z + v.z, 0.f);
      w.w = fmaxf(w.w + v.w, 0.f);
      *(float4*)(mr + j * 4) = w;
    }
  }
  __syncthreads();                           // S5: messages final

  // ---- per-column run walk: 128 cols x 2 threads (runs split by parity).
  // Interior runs are exclusive to this block (dst-sorted) -> plain store;
  // runs touching row 0 or 127 may continue in neighbor blocks -> atomic.
  {
    const int col = tid & 127;
    const int h = tid >> 7;
    const int nR = nRunsS;
    for (int i = h; i < nR; i += 2){
      int s = runStart[i], e = runStart[i + 1];
      int dst = (int)sE[s].z;
      float run = 0.f;
      for (int r = s; r < e; ++r) run += msgS[r * 132 + col];
      size_t a = (size_t)dst * IN_C + col;
      if (s == 0 || e == 128) atomicAdd(&agg[a], run);
      else                    agg[a] = run;
    }
  }
}

// ---------------- h0 = agg + x -> bf16 ----------------
__global__ __launch_bounds__(256) void k_h0(const float* __restrict__ agg,
                                            const float* __restrict__ x,
                                            unsigned short* __restrict__ h0b){
  int i = blockIdx.x * 256 + threadIdx.x;
  if (i < NN * IN_C) h0b[i] = f2bs(agg[i] + x[i]);
}

// ---------------- MFMA GEMM with LDS-staged fragments --------------------
// out[m][c] = A[m][:K].Wt[c][:K] + bias[c]; block 64m x 128n, 4 waves 2x2.
template<int K, bool RELU, bool OF32, bool OB16>
__global__ __launch_bounds__(256) void k_gemm(
    const unsigned short* __restrict__ A, const unsigned short* __restrict__ Wt,
    const float* __restrict__ bias, float* __restrict__ outf,
    unsigned short* __restrict__ outb, int M, int Ntot)
{
  __shared__ unsigned short aS[64 * 40];
  __shared__ unsigned short bS[128 * 40];
  const int tid = threadIdx.x;
  const int lane = tid & 63, wv = tid >> 6;
  const int wi = wv >> 1, wj = wv & 1;
  const int q = lane >> 4, l15 = lane & 15;
  const int mb0 = blockIdx.x * 64;
  const int nb0 = blockIdx.y * 128;
  const int arow = tid >> 2, achk = tid & 3;

  f4acc acc[2][4];
  const f4acc zz = {0.f, 0.f, 0.f, 0.f};
#pragma unroll
  for (int mt = 0; mt < 2; ++mt)
#pragma unroll
    for (int nt = 0; nt < 4; ++nt) acc[mt][nt] = zz;

  for (int ks = 0; ks < K / 32; ++ks){
    {
      int m = mb0 + arow; if (m >= M) m = M - 1;
      const uint4 v = *(const uint4*)(A + (size_t)m * K + ks * 32 + achk * 8);
      *(uint4*)&aS[arow * 40 + achk * 8] = v;
    }
#pragma unroll
    for (int i = 0; i < 2; ++i){
      int idx = i * 256 + tid;
      int row = idx >> 2, chk = idx & 3;
      const uint4 v = *(const uint4*)(Wt + (size_t)(nb0 + row) * K + ks * 32 + chk * 8);
      *(uint4*)&bS[row * 40 + chk * 8] = v;
    }
    __syncthreads();
    bfrag a[2], b[4];
#pragma unroll
    for (int mt = 0; mt < 2; ++mt)
      a[mt] = *(const bfrag*)&aS[(wi * 32 + mt * 16 + l15) * 40 + q * 8];
#pragma unroll
    for (int nt = 0; nt < 4; ++nt)
      b[nt] = *(const bfrag*)&bS[(wj * 64 + nt * 16 + l15) * 40 + q * 8];
#pragma unroll
    for (int mt = 0; mt < 2; ++mt)
#pragma unroll
      for (int nt = 0; nt < 4; ++nt)
        acc[mt][nt] = __builtin_amdgcn_mfma_f32_16x16x32_bf16(a[mt], b[nt], acc[mt][nt], 0, 0, 0);
    __syncthreads();
  }

  const int mb = mb0 + wi * 32;
  const int nb = nb0 + wj * 64;
#pragma unroll
  for (int nt = 0; nt < 4; ++nt){
    int c = nb + nt * 16 + l15;
    float bv = bias[c];
#pragma unroll
    for (int mt = 0; mt < 2; ++mt){
#pragma unroll
      for (int r = 0; r < 4; ++r){
        int m = mb + mt * 16 + q * 4 + r;
        if (m < M){
          float v = acc[mt][nt][r] + bv;
          if (RELU) v = v > 0.f ? v : 0.f;
          if (OF32) outf[(size_t)m * Ntot + c] = v;
          if (OB16) outb[(size_t)m * Ntot + c] = f2bs(v);
        }
      }
    }
  }
}

// ---------------- gate2: gate[r] = g1[r,:128].Wg2 + bg2 (wave/row) -------
__global__ __launch_bounds__(256) void k_gate2(const float* __restrict__ g1,
                                               const float* __restrict__ Wg2,
                                               const float* __restrict__ bg2,
                                               float* __restrict__ gate, int nrows){
  const int lane = threadIdx.x & 63, wv = threadIdx.x >> 6;
  const float2 w2 = *(const float2*)(Wg2 + lane * 2);
  const float bg = bg2[0];
  for (int r = blockIdx.x * 4 + wv; r < nrows; r += gridDim.x * 4){
    const float2 a2 = *(const float2*)(g1 + (size_t)r * G1_C + lane * 2);
    float p = a2.x * w2.x + a2.y * w2.y;
#pragma unroll
    for (int off = 32; off > 0; off >>= 1) p += __shfl_down(p, off);
    if (lane == 0) gate[r] = p + bg;
  }
}

// ---------------- segment max (batch sorted; block pre-reduce) ----------
__global__ __launch_bounds__(256) void k_gmax(const float* __restrict__ gate,
                                              const int* __restrict__ batch,
                                              float* __restrict__ gmax, int nrows){
  __shared__ float red[256];
  const int tid = threadIdx.x;
  const int n0 = blockIdx.x * 256;
  const int n = n0 + tid;
  const int nlast = (n0 + 255 < nrows) ? n0 + 255 : nrows - 1;
  const int bmin = batch[n0], bmax = batch[nlast];
  float val = -3e38f; int b = bmax;
  if (n < nrows){ b = batch[n]; val = gate[n]; }
  for (int bb = bmin; bb <= bmax; ++bb){
    red[tid] = (b == bb) ? val : -3e38f;
    __syncthreads();
    for (int s = 128; s > 0; s >>= 1){
      if (tid < s) red[tid] = fmaxf(red[tid], red[tid + s]);
      __syncthreads();
    }
    if (tid == 0 && red[0] > -1e37f) atomicMaxFloat(&gmax[bb], red[0]);
    __syncthreads();
  }
}

// ---------------- a = exp(gate - gmax[b]); denom[b] += a ----------------
__global__ __launch_bounds__(256) void k_expsum(const float* __restrict__ gate,
                                                const int* __restrict__ batch,
                                                const float* __restrict__ gmax,
                                                float* __restrict__ aexp,
                                                float* __restrict__ denom, int nrows){
  __shared__ float red[256];
  const int tid = threadIdx.x;
  const int n0 = blockIdx.x * 256;
  const int n = n0 + tid;
  const int nlast = (n0 + 255 < nrows) ? n0 + 255 : nrows - 1;
  const int bmin = batch[n0], bmax = batch[nlast];
  float val = 0.f; int b = bmax;
  if (n < nrows){
    b = batch[n];
    val = expf(gate[n] - gmax[b]);
    aexp[n] = val;
  }
  for (int bb = bmin; bb <= bmax; ++bb){
    red[tid] = (b == bb) ? val : 0.f;
    __syncthreads();
    for (int s = 128; s > 0; s >>= 1){
      if (tid < s) red[tid] += red[tid + s];
      __syncthreads();
    }
    if (tid == 0 && red[0] != 0.f) atomicAdd(&denom[bb], red[0]);
    __syncthreads();
  }
}

// ---------------- pooled[b] += (a/denom[b]) * h2[n] ----------------
__global__ __launch_bounds__(256) void k_pool(const unsigned short* __restrict__ h2b,
                                              const float* __restrict__ aexp,
                                              const float* __restrict__ denom,
                                              const int* __restrict__ batch,
                                              float* __restrict__ pooled, int nrows){
  const int c = threadIdx.x;
  const int n0 = blockIdx.x * 256;
  int n1 = n0 + 256; if (n1 > nrows) n1 = nrows;
  float acc = 0.f;
  int curb = batch[n0];
  for (int n = n0; n < n1; ++n){
    int b = batch[n];
    if (b != curb){
      atomicAdd(&pooled[(size_t)curb * HID_C + c], acc);
      acc = 0.f; curb = b;
    }
    float wgt = aexp[n] / denom[b];
    acc = fmaf(wgt, bs2f(h2b[(size_t)n * HID_C + c]), acc);
  }
  atomicAdd(&pooled[(size_t)curb * HID_C + c], acc);
}

// ---------------- head: logits = pooled @ Wh + bh ----------------
__global__ __launch_bounds__(256) void k_head(const float* __restrict__ pooled,
                                              const float* __restrict__ Wh,
                                              const float* __restrict__ bh,
                                              float* __restrict__ out_logits,
                                              float* __restrict__ out_pooled){
  __shared__ float p[HID_C];
  const int b = blockIdx.x, t = threadIdx.x;
  float pv = pooled[(size_t)b * HID_C + t];
  p[t] = pv;
  out_pooled[(size_t)b * HID_C + t] = pv;
  __syncthreads();
  for (int c = t; c < KK; c += 256){
    float acc = bh[c];
#pragma unroll 8
    for (int k = 0; k < HID_C; ++k)
      acc = fmaf(p[k], Wh[k * KK + c], acc);
    out_logits[(size_t)b * KK + c] = acc;
  }
}

extern "C" void kernel_launch(void* const* d_in, const int* in_sizes, int n_in,
                              void* d_out, int out_size, void* d_ws, size_t ws_size,
                              hipStream_t stream) {
  const float* x   = (const float*)d_in[0];
  const int*   ei  = (const int*)d_in[1];
  const float* ea  = (const float*)d_in[2];
  const int*   batch = (const int*)d_in[3];
  const float* We  = (const float*)d_in[4];
  const float* be  = (const float*)d_in[5];
  const float* W1  = (const float*)d_in[6];
  const float* b1  = (const float*)d_in[7];
  const float* W2  = (const float*)d_in[8];
  const float* b2  = (const float*)d_in[9];
  const float* Wg1 = (const float*)d_in[10];
  const float* bg1 = (const float*)d_in[11];
  const float* Wg2 = (const float*)d_in[12];
  const float* bg2 = (const float*)d_in[13];
  const float* Wh  = (const float*)d_in[14];
  const float* bh  = (const float*)d_in[15];

  float* out_logits = (float*)d_out;
  float* out_pooled = out_logits + (size_t)BB * KK;

  // ws layout: f32 region | h0b | h1b (aliased by sort scratch) | h2b | weights
  float* agg    = (float*)d_ws;                    // N*128 (g1f alias later)
  float* gate   = agg   + (size_t)NN * IN_C;       // N
  float* aexp   = gate  + NN;                      // N
  float* gmax   = aexp  + NN;                      // B
  float* denom  = gmax  + BB;                      // B
  float* pooled = denom + BB;                      // B*256
  float* fend   = pooled + (size_t)BB * HID_C;     // 16B-aligned
  unsigned short* h0b  = (unsigned short*)fend;    // N*128 bf16
  unsigned short* h1b  = h0b + (size_t)NN * IN_C;  // N*256 bf16 (25.6MB)
  unsigned short* h2b  = h1b + (size_t)NN * HID_C; // N*256 bf16
  unsigned short* Wet  = h2b + (size_t)NN * HID_C; // 128*64
  unsigned short* W1t  = Wet + 128 * 64;
  unsigned short* W2t  = W1t + 256 * 128;
  unsigned short* Wg1t = W2t + 256 * 256;
  float* g1f = agg;                                // alias: agg dead after k_h0
  // sort scratch aliases h1b region (dead until gemm1): 12.8MB + 0.6MB < 25.6MB
  uint4* sorted = (uint4*)h1b;                     // EE * 16B
  int* cnt  = (int*)(sorted + EE);                 // NV
  int* off  = cnt + NV;                            // NV
  int* fill = off + NV;                            // NV
  int* aux  = fill + NV;                           // 256

  k_prep<<<256, 256, 0, stream>>>(We, W1, W2, Wg1, Wet, W1t, W2t, Wg1t);
  k_init<<<(NN * IN_C + 255) / 256, 256, 0, stream>>>(agg, cnt, fill, aux, gmax, denom, pooled);
  // counting sort by dst
  k_hist   <<<(EE + 255) / 256, 256, 0, stream>>>(ei, cnt);
  k_scan1  <<<NV / 256, 256, 0, stream>>>(cnt, off, aux);
  k_scan2  <<<1, 256, 0, stream>>>(aux);
  k_scan3  <<<NV / 256, 256, 0, stream>>>(off, aux);
  k_scatter<<<(EE + 255) / 256, 256, 0, stream>>>(ei, off, fill, sorted);
  // edge projection + message + run-list segmented-reduce scatter
  k_edge2<<<EE / 128, 256, 0, stream>>>(x, sorted, ea, Wet, be, agg);
  k_h0<<<(NN * IN_C + 255) / 256, 256, 0, stream>>>(agg, x, h0b);
  // MLP + gate GEMMs (sort scratch dead from here; h1b reused)
  k_gemm<128, true,  false, true ><<<dim3(782, 2), 256, 0, stream>>>(h0b, W1t, b1, (float*)0, h1b, NN, HID_C);
  k_gemm<256, false, false, true ><<<dim3(782, 2), 256, 0, stream>>>(h1b, W2t, b2, (float*)0, h2b, NN, HID_C);
  k_gemm<256, true,  true,  false><<<dim3(782, 1), 256, 0, stream>>>(h2b, Wg1t, bg1, g1f, (unsigned short*)0, NN, G1_C);
  k_gate2<<<3125, 256, 0, stream>>>(g1f, Wg2, bg2, gate, NN);
  k_gmax  <<<(NN + 255) / 256, 256, 0, stream>>>(gate, batch, gmax, NN);
  k_expsum<<<(NN + 255) / 256, 256, 0, stream>>>(gate, batch, gmax, aexp, denom, NN);
  k_pool  <<<(NN + 255) / 256, 256, 0, stream>>>(h2b, aexp, denom, batch, pooled, NN);
  k_head<<<BB, 256, 0, stream>>>(pooled, Wh, bh, out_logits, out_pooled);
}